// Round 9
// baseline (388.722 us; speedup 1.0000x reference)
//
#include <hip/hip_runtime.h>
#include <float.h>
#include <math.h>

#define EPS 1e-5f
constexpr int B = 4, C = 3, N = 4096, E = 256;
constexpr int KNN = 15;            // 15 neighbors kept (top-16 minus rank 0)
constexpr int BN_ = B * N;         // 16384
constexpr int P = 4;               // points per block in fused kernel
constexpr int SR  = 264;           // hh_bf row stride (ushorts)
constexpr int SRF = 520;           // feat_bf row stride (ushorts)

typedef short bf8 __attribute__((ext_vector_type(8)));   // 8 bf16 in 4 VGPRs
typedef float f4  __attribute__((ext_vector_type(4)));

static __device__ __forceinline__ unsigned short f2bf(float f) {
    union { float f; unsigned int u; } v; v.f = f;
    unsigned int r = v.u + 0x7FFFu + ((v.u >> 16) & 1u);   // RTNE
    return (unsigned short)(r >> 16);
}
static __device__ __forceinline__ bf8 ld_bf8(const unsigned short* p) {
    return *(const bf8*)p;
}
// tanh-GELU: gelu(v) = v*(1 - 1/(1+exp(2u))), u = 0.79788456(v + 0.044715 v^3)
// max |err| vs exact erf-gelu ~3e-4 (<< bf16 rounding). 8 VALU inst, 2 transcendental.
static __device__ __forceinline__ float gelu_t(float v) {
    float z = v * fmaf(v * v, 0.07135482f, 1.59576912f);   // z = 2u
    float r = __builtin_amdgcn_rcpf(1.f + __expf(z));
    return fmaf(-v, r, v);
}

// ---------------- K1: per-channel mean/rstd of x over (B,N) ----------------
__global__ void bn1_stats(const float* __restrict__ x, float* __restrict__ bn1) {
    int c = blockIdx.x, t = threadIdx.x;
    float s = 0.f, ss = 0.f;
    for (int i4 = t; i4 < BN_ / 4; i4 += 256) {
        int b = i4 >> 10, n4 = i4 & 1023;
        float4 v = ((const float4*)(x + (b * C + c) * N))[n4];
        s += v.x + v.y + v.z + v.w;
        ss += v.x * v.x + v.y * v.y + v.z * v.z + v.w * v.w;
    }
    __shared__ float rs_[256], rss_[256];
    rs_[t] = s; rss_[t] = ss; __syncthreads();
    for (int w = 128; w > 0; w >>= 1) {
        if (t < w) { rs_[t] += rs_[t + w]; rss_[t] += rss_[t + w]; }
        __syncthreads();
    }
    if (t == 0) {
        float mu = rs_[0] / (float)BN_;
        float var = rss_[0] / (float)BN_ - mu * mu;
        bn1[c] = mu; bn1[3 + c] = rsqrtf(var + EPS);
    }
}

// ---------------- K2: xn4 AoS (blocks 0..63) + tile-lane-major bf16 weights ----------------
// w2b_t: chunk (ft16*8+kb)*64+lane holds W2b[ft16*16+(lane&15)][kb*32+(lane>>4)*8 ..+8]
// wf_t : chunk (ot*16+kb)*64+lane holds Wf[ot*16+(lane&15)][kb*32+(lane>>4)*8 ..+8]
__global__ void compute_xn_cvt(const float* __restrict__ x,
                               const float* __restrict__ g1,
                               const float* __restrict__ b1,
                               const float* __restrict__ bn1,
                               float4* __restrict__ xn4,
                               const float* __restrict__ W2b, const float* __restrict__ Wf,
                               unsigned short* __restrict__ w2b_t, unsigned short* __restrict__ wf_t) {
    int blk = blockIdx.x;
    if (blk < BN_ / 256) {
        int i = blk * 256 + threadIdx.x;
        int b = i >> 12, n = i & (N - 1);
        float v[3];
        #pragma unroll
        for (int c = 0; c < C; c++)
            v[c] = (x[(b * C + c) * N + n] - bn1[c]) * bn1[3 + c] * g1[c] + b1[c];
        float4 o; o.x = v[0]; o.y = v[1]; o.z = v[2];
        o.w = v[0] * v[0] + v[1] * v[1] + v[2] * v[2];
        xn4[i] = o;
        return;
    }
    int ch = (blk - BN_ / 256) * 256 + threadIdx.x;   // chunk id (8 bf16 per chunk)
    if (ch < 8192) {               // w2b: 65536 elems = 8192 chunks
        int lane = ch & 63, kb = (ch >> 6) & 7, ft16 = ch >> 9;
        int row = ft16 * 16 + (lane & 15);
        int col = kb * 32 + (lane >> 4) * 8;
        #pragma unroll
        for (int j = 0; j < 8; j++)
            w2b_t[ch * 8 + j] = f2bf(W2b[row * 256 + col + j]);
    } else {                       // wf: 131072 elems = 16384 chunks
        int c2 = ch - 8192;
        int lane = c2 & 63, kb = (c2 >> 6) & 15, ot = c2 >> 10;
        int row = ot * 16 + (lane & 15);
        int col = kb * 32 + (lane >> 4) * 8;
        #pragma unroll
        for (int j = 0; j < 8; j++)
            wf_t[c2 * 8 + j] = f2bf(Wf[row * 512 + col + j]);
    }
}

// ---------------- K3: top-16 (largest d2), one WAVE per point, no barriers ----------------
__global__ void __launch_bounds__(256, 4) knn_kernel(const float4* __restrict__ xn4,
                                                     unsigned short* __restrict__ idxout,
                                                     float* __restrict__ S9) {
    __shared__ float smom[4][15][9];
    int w = threadIdx.x >> 6, lane = threadIdx.x & 63;
    int i = blockIdx.x * 4 + w;
    int b = i >> 12, n = i & (N - 1);
    const float4* xb = xn4 + b * N;
    float4 qv = xb[n];
    float d[64];
    #pragma unroll
    for (int s = 0; s < 64; s++) {
        float4 p = xb[s * 64 + lane];
        d[s] = qv.w + p.w - 2.f * (qv.x * p.x + qv.y * p.y + qv.z * p.z);
    }
    float cm[8];
    #pragma unroll
    for (int c = 0; c < 8; c++) {
        float v = d[c * 8];
        #pragma unroll
        for (int s = 1; s < 8; s++) v = fmaxf(v, d[c * 8 + s]);
        cm[c] = v;
    }
    float bv = cm[0];
    #pragma unroll
    for (int c = 1; c < 8; c++) bv = fmaxf(bv, cm[c]);

    int myj = 0;
    for (int r = 0; r < 16; r++) {
        float wv = bv;
        #pragma unroll
        for (int off = 32; off > 0; off >>= 1)
            wv = fmaxf(wv, __shfl_xor(wv, off));
        unsigned long long msk = __ballot(bv == wv);
        int wl = __ffsll(msk) - 1;
        int gi = 0;
        if (lane == wl) {
            int cstar = 0; bool got = false;
            #pragma unroll
            for (int c = 0; c < 8; c++) {
                bool h = !got && (cm[c] == bv);
                cstar = h ? c : cstar;
                got = got || h;
            }
            int slot = 0;
            #pragma unroll
            for (int c = 0; c < 8; c++) {
                if (c == cstar) {   // 7 of 8 bodies skipped via execz
                    bool g2 = false;
                    #pragma unroll
                    for (int s = 0; s < 8; s++) {
                        bool h = !g2 && (d[c * 8 + s] == bv);
                        slot = h ? (c * 8 + s) : slot;
                        g2 = g2 || h;
                    }
                    #pragma unroll
                    for (int s = 0; s < 8; s++)
                        d[c * 8 + s] = (c * 8 + s == slot) ? -FLT_MAX : d[c * 8 + s];
                    float v = d[c * 8];
                    #pragma unroll
                    for (int s = 1; s < 8; s++) v = fmaxf(v, d[c * 8 + s]);
                    cm[c] = v;
                }
            }
            bv = cm[0];
            #pragma unroll
            for (int c = 1; c < 8; c++) bv = fmaxf(bv, cm[c]);
            gi = slot * 64 + lane;
        }
        int g = __shfl(gi, wl);
        if (lane == r - 1) myj = g;   // lanes 0..14 capture ranks 1..15
    }

    bool act = lane < 15;
    if (act) idxout[i * KNN + lane] = (unsigned short)myj;
    float4 pj = xb[act ? myj : n];
    float v0 = pj.x - qv.x, v1 = pj.y - qv.y, v2 = pj.z - qv.z;
    if (act) {
        float* mm = smom[w][lane];
        mm[0] = v0; mm[1] = v1; mm[2] = v2;
        mm[3] = v0 * v0; mm[4] = v1 * v1; mm[5] = v2 * v2;
        mm[6] = v0 * v1; mm[7] = v0 * v2; mm[8] = v1 * v2;
    }
    __syncthreads();
    int t = threadIdx.x;
    if (t < 36) {
        int wsel = t / 9, j = t % 9;
        float a = 0.f;
        #pragma unroll
        for (int u = 0; u < 15; u++) a += smom[wsel][u][j];
        atomicAdd(&S9[((blockIdx.x * 4 + wsel) & 63) * 9 + j], a);
    }
}

// ---------------- K5: closed-form BN2a affine + per-E fused (W2a*s, shift) float4 ----------------
__global__ void finalize_stats(const float* __restrict__ S9,
                               const float* __restrict__ g2a, const float* __restrict__ b2a,
                               const float* __restrict__ W2a,
                               const float* __restrict__ g2b, const float* __restrict__ b2b,
                               float* __restrict__ ab, float4* __restrict__ wsb) {
    const float cnt = (float)(BN_ * KNN);
    __shared__ float S[9];
    __shared__ float alpha[3], beta[3], mu[3], Ehh[3][3];
    int t = threadIdx.x;
    if (t < 9) {
        float a = 0.f;
        for (int u = 0; u < 64; u++) a += S9[u * 9 + t];
        S[t] = a;
    }
    __syncthreads();
    if (t == 0) {
        float m[3];
        float s2[3][3];
        s2[0][0] = S[3]; s2[1][1] = S[4]; s2[2][2] = S[5];
        s2[0][1] = s2[1][0] = S[6]; s2[0][2] = s2[2][0] = S[7]; s2[1][2] = s2[2][1] = S[8];
        for (int c = 0; c < 3; c++) {
            m[c] = S[c] / cnt;
            float var = s2[c][c] / cnt - m[c] * m[c];
            alpha[c] = g2a[c] * rsqrtf(var + EPS);
            beta[c]  = b2a[c] - m[c] * alpha[c];
            mu[c] = m[c];
            ab[c] = alpha[c]; ab[3 + c] = beta[c];
        }
        for (int c = 0; c < 3; c++)
            for (int cc = 0; cc < 3; cc++)
                Ehh[c][cc] = alpha[c] * alpha[cc] * (s2[c][cc] / cnt)
                           + alpha[c] * beta[cc] * m[c]
                           + beta[c] * alpha[cc] * m[cc]
                           + beta[c] * beta[cc];
    }
    __syncthreads();
    int e = t;
    float wv[3], Eh[3];
    for (int c = 0; c < 3; c++) { wv[c] = W2a[e * 3 + c]; Eh[c] = alpha[c] * mu[c] + beta[c]; }
    float mean = wv[0] * Eh[0] + wv[1] * Eh[1] + wv[2] * Eh[2];
    float m2 = 0.f;
    for (int c = 0; c < 3; c++)
        for (int cc = 0; cc < 3; cc++) m2 += wv[c] * wv[cc] * Ehh[c][cc];
    float var = m2 - mean * mean;
    float s = g2b[e] * rsqrtf(var + EPS);
    float4 o;
    o.x = wv[0] * s; o.y = wv[1] * s; o.z = wv[2] * s; o.w = b2b[e] - mean * s;
    wsb[e] = o;
}

// ---------------- K6: fused W2a→BN2b→gelu→[MFMA W2b]→max | point_emb | [MFMA Wf] ----------------
// Phase C waves split f into quarters and cover ALL 4 points -> w2b loaded once per block.
__global__ void __launch_bounds__(256, 4) fused_final(
        const float4* __restrict__ xn4, const unsigned short* __restrict__ idx,
        const float* __restrict__ ab,
        const float4* __restrict__ wsb,
        const unsigned short* __restrict__ w2b_t,
        const float* __restrict__ W1, const float* __restrict__ bw1,
        const unsigned short* __restrict__ wf_t, const float* __restrict__ bfv,
        float* __restrict__ out) {
    __shared__ __align__(16) unsigned short hh_bf[64 * SR];    // row n=16p+k, col e (bf16)
    __shared__ __align__(16) unsigned short feat_bf[4 * SRF];  // row p, col f 0..511 (bf16)
    __shared__ __align__(16) float4 hhat4[P][16];              // (h0,h1,h2,-) per (p,k)
    int i0 = blockIdx.x * P;
    int t = threadIdx.x;
    int b = i0 >> 12, n0 = i0 & (N - 1);
    const float4* xb = xn4 + b * N;

    if (t < P * KNN) {   // phase A: gather + BN2a affine
        int p = t / KNN, k = t % KNN;
        int j = idx[(i0 + p) * KNN + k];
        float4 pj = xb[j];
        float4 pn = xb[n0 + p];
        float4 h;
        h.x = ab[0] * (pj.x - pn.x) + ab[3];
        h.y = ab[1] * (pj.y - pn.y) + ab[4];
        h.z = ab[2] * (pj.z - pn.z) + ab[5];
        h.w = 0.f;
        hhat4[p][k] = h;
    }
    __syncthreads();

    {   // phase B: h = (W2a*s) @ hhat + shift, tanh-gelu (bf16 to LDS); point_emb
        int e = t;
        float4 w4 = wsb[e];   // (w0*s, w1*s, w2*s, shift)
        #pragma unroll
        for (int p = 0; p < P; p++) {
            float g0 = 0.f;
            #pragma unroll
            for (int k = 0; k < KNN; k++) {
                float4 hv = hhat4[p][k];
                float v = fmaf(w4.x, hv.x, fmaf(w4.y, hv.y, fmaf(w4.z, hv.z, w4.w)));
                float g = gelu_t(v);
                hh_bf[(16 * p + k) * SR + e] = f2bf(g);
                if (k == 0) g0 = g;
            }
            hh_bf[(16 * p + 15) * SR + e] = f2bf(g0);   // dup row: max unaffected
            float4 pv = xb[n0 + p];
            feat_bf[p * SRF + e] = f2bf(bw1[e] + W1[e * 3] * pv.x
                       + W1[e * 3 + 1] * pv.y + W1[e * 3 + 2] * pv.z);
        }
    }
    __syncthreads();

    int w = t >> 6, lane = t & 63;
    int m = lane & 15, q = lane >> 4;

    {   // phase C: wave w owns f-tiles w*4..w*4+3, all 4 points (w2b loaded once/block)
        for (int ftl = 0; ftl < 4; ftl++) {
            int ftg = w * 4 + ftl;
            bf8 a[8];
            #pragma unroll
            for (int kb = 0; kb < 8; kb++)
                a[kb] = ld_bf8(w2b_t + ftg * 4096 + kb * 512 + lane * 8);
            #pragma unroll
            for (int pi = 0; pi < 4; pi++) {
                f4 acc = {0.f, 0.f, 0.f, 0.f};
                #pragma unroll
                for (int kb = 0; kb < 8; kb++) {
                    bf8 h = ld_bf8(&hh_bf[(16 * pi + m) * SR + kb * 32 + q * 8]);
                    acc = __builtin_amdgcn_mfma_f32_16x16x32_bf16(h, a[kb], acc, 0, 0, 0);
                }
                float mx = fmaxf(fmaxf(acc[0], acc[1]), fmaxf(acc[2], acc[3]));
                mx = fmaxf(mx, __shfl_xor(mx, 16));
                mx = fmaxf(mx, __shfl_xor(mx, 32));
                if (lane < 16)
                    feat_bf[pi * SRF + E + ftg * 16 + lane] = f2bf(mx);
            }
        }
    }
    __syncthreads();

    {   // phase D: out = Wf @ feat^T via MFMA (cols = points; feat fragments hoisted)
        bf8 fb[16];
        #pragma unroll
        for (int kb = 0; kb < 16; kb++)
            fb[kb] = ld_bf8(&feat_bf[(m & 3) * SRF + kb * 32 + q * 8]);
        const unsigned short* wfb = wf_t + w * 4 * 8192 + lane * 8;
        #pragma unroll
        for (int ot = 0; ot < 4; ot++) {
            f4 acc = {0.f, 0.f, 0.f, 0.f};
            #pragma unroll
            for (int kb = 0; kb < 16; kb++) {
                bf8 a = ld_bf8(wfb + ot * 8192 + kb * 512);
                acc = __builtin_amdgcn_mfma_f32_16x16x32_bf16(a, fb[kb], acc, 0, 0, 0);
            }
            if (m < P) {   // col = m = point; row = obase + 4q + reg
                int o0 = (w * 4 + ot) * 16 + 4 * q;
                out[(b * E + o0 + 0) * N + n0 + m] = acc[0] + bfv[o0 + 0];
                out[(b * E + o0 + 1) * N + n0 + m] = acc[1] + bfv[o0 + 1];
                out[(b * E + o0 + 2) * N + n0 + m] = acc[2] + bfv[o0 + 2];
                out[(b * E + o0 + 3) * N + n0 + m] = acc[3] + bfv[o0 + 3];
            }
        }
    }
}

extern "C" void kernel_launch(void* const* d_in, const int* in_sizes, int n_in,
                              void* d_out, int out_size, void* d_ws, size_t ws_size,
                              hipStream_t stream) {
    (void)in_sizes; (void)n_in; (void)out_size; (void)ws_size;
    const float* x   = (const float*)d_in[0];
    const float* g1  = (const float*)d_in[1];
    const float* b1  = (const float*)d_in[2];
    const float* W1  = (const float*)d_in[3];
    const float* bw1 = (const float*)d_in[4];
    const float* g2a = (const float*)d_in[5];
    const float* b2a = (const float*)d_in[6];
    const float* W2a = (const float*)d_in[7];
    const float* g2b = (const float*)d_in[8];
    const float* b2b = (const float*)d_in[9];
    const float* W2b = (const float*)d_in[10];
    const float* Wf  = (const float*)d_in[11];
    const float* bfv = (const float*)d_in[12];
    float* out = (float*)d_out;

    char* ws = (char*)d_ws;
    size_t off = 0;
    auto alloc = [&](size_t bytes) { size_t o = off; off = (off + bytes + 255) & ~(size_t)255; return o; };
    float4* xn4           = (float4*)(ws + alloc(sizeof(float4) * BN_));
    unsigned short* idx   = (unsigned short*)(ws + alloc(sizeof(unsigned short) * BN_ * KNN));
    float* bn1            = (float*)(ws + alloc(sizeof(float) * 8));
    float* S9             = (float*)(ws + alloc(sizeof(float) * 64 * 9));
    float* ab             = (float*)(ws + alloc(sizeof(float) * 8));
    float4* wsb           = (float4*)(ws + alloc(sizeof(float4) * E));
    unsigned short* w2bt  = (unsigned short*)(ws + alloc(sizeof(unsigned short) * E * E));
    unsigned short* wft   = (unsigned short*)(ws + alloc(sizeof(unsigned short) * E * 2 * E));

    hipMemsetAsync(S9, 0, sizeof(float) * 64 * 9, stream);

    bn1_stats<<<C, 256, 0, stream>>>(x, bn1);
    compute_xn_cvt<<<BN_ / 256 + (8192 + 16384) / 256, 256, 0, stream>>>(
        x, g1, b1, bn1, xn4, W2b, Wf, w2bt, wft);
    knn_kernel<<<BN_ / 4, 256, 0, stream>>>(xn4, idx, S9);
    finalize_stats<<<1, 256, 0, stream>>>(S9, g2a, b2a, W2a, g2b, b2b, ab, wsb);
    fused_final<<<BN_ / P, 256, 0, stream>>>(xn4, idx, ab, wsb, w2bt, W1, bw1, wft, bfv, out);
}

// Round 10
// 262.481 us; speedup vs baseline: 1.4809x; 1.4809x over previous
//
#include <hip/hip_runtime.h>
#include <float.h>
#include <math.h>

#define EPS 1e-5f
constexpr int B = 4, C = 3, N = 4096, E = 256;
constexpr int KNN = 15;            // 15 neighbors kept (top-16 minus rank 0)
constexpr int BN_ = B * N;         // 16384
constexpr int P = 4;               // points per block in fused kernel
constexpr int SR  = 264;           // hh_bf row stride (ushorts)
constexpr int SRF = 520;           // feat_bf row stride (ushorts)

typedef short bf8 __attribute__((ext_vector_type(8)));   // 8 bf16 in 4 VGPRs
typedef float f4  __attribute__((ext_vector_type(4)));

static __device__ __forceinline__ unsigned short f2bf(float f) {
    union { float f; unsigned int u; } v; v.f = f;
    unsigned int r = v.u + 0x7FFFu + ((v.u >> 16) & 1u);   // RTNE
    return (unsigned short)(r >> 16);
}
static __device__ __forceinline__ bf8 ld_bf8(const unsigned short* p) {
    return *(const bf8*)p;
}
// tanh-GELU: gelu(v) = v*(1 - 1/(1+exp(2u))), u = 0.79788456(v + 0.044715 v^3)
// max |err| vs exact erf-gelu ~3e-4 (<< bf16 rounding).
static __device__ __forceinline__ float gelu_t(float v) {
    float z = v * fmaf(v * v, 0.07135482f, 1.59576912f);   // z = 2u
    float r = __builtin_amdgcn_rcpf(1.f + __expf(z));
    return fmaf(-v, r, v);
}

// ---------------- K1: per-channel mean/rstd of x over (B,N) ----------------
__global__ void bn1_stats(const float* __restrict__ x, float* __restrict__ bn1) {
    int c = blockIdx.x, t = threadIdx.x;
    float s = 0.f, ss = 0.f;
    for (int i4 = t; i4 < BN_ / 4; i4 += 256) {
        int b = i4 >> 10, n4 = i4 & 1023;
        float4 v = ((const float4*)(x + (b * C + c) * N))[n4];
        s += v.x + v.y + v.z + v.w;
        ss += v.x * v.x + v.y * v.y + v.z * v.z + v.w * v.w;
    }
    __shared__ float rs_[256], rss_[256];
    rs_[t] = s; rss_[t] = ss; __syncthreads();
    for (int w = 128; w > 0; w >>= 1) {
        if (t < w) { rs_[t] += rs_[t + w]; rss_[t] += rss_[t + w]; }
        __syncthreads();
    }
    if (t == 0) {
        float mu = rs_[0] / (float)BN_;
        float var = rss_[0] / (float)BN_ - mu * mu;
        bn1[c] = mu; bn1[3 + c] = rsqrtf(var + EPS);
    }
}

// ---------------- K2: xn4 AoS (blocks 0..63) + tile-lane-major bf16 weights ----------------
// w2b_t: chunk (ft16*8+kb)*64+lane holds W2b[ft16*16+(lane&15)][kb*32+(lane>>4)*8 ..+8]
// wf_t : chunk (ot*16+kb)*64+lane holds Wf[ot*16+(lane&15)][kb*32+(lane>>4)*8 ..+8]
__global__ void compute_xn_cvt(const float* __restrict__ x,
                               const float* __restrict__ g1,
                               const float* __restrict__ b1,
                               const float* __restrict__ bn1,
                               float4* __restrict__ xn4,
                               const float* __restrict__ W2b, const float* __restrict__ Wf,
                               unsigned short* __restrict__ w2b_t, unsigned short* __restrict__ wf_t) {
    int blk = blockIdx.x;
    if (blk < BN_ / 256) {
        int i = blk * 256 + threadIdx.x;
        int b = i >> 12, n = i & (N - 1);
        float v[3];
        #pragma unroll
        for (int c = 0; c < C; c++)
            v[c] = (x[(b * C + c) * N + n] - bn1[c]) * bn1[3 + c] * g1[c] + b1[c];
        float4 o; o.x = v[0]; o.y = v[1]; o.z = v[2];
        o.w = v[0] * v[0] + v[1] * v[1] + v[2] * v[2];
        xn4[i] = o;
        return;
    }
    int ch = (blk - BN_ / 256) * 256 + threadIdx.x;   // chunk id (8 bf16 per chunk)
    if (ch < 8192) {               // w2b: 65536 elems = 8192 chunks
        int lane = ch & 63, kb = (ch >> 6) & 7, ft16 = ch >> 9;
        int row = ft16 * 16 + (lane & 15);
        int col = kb * 32 + (lane >> 4) * 8;
        #pragma unroll
        for (int j = 0; j < 8; j++)
            w2b_t[ch * 8 + j] = f2bf(W2b[row * 256 + col + j]);
    } else {                       // wf: 131072 elems = 16384 chunks
        int c2 = ch - 8192;
        int lane = c2 & 63, kb = (c2 >> 6) & 15, ot = c2 >> 10;
        int row = ot * 16 + (lane & 15);
        int col = kb * 32 + (lane >> 4) * 8;
        #pragma unroll
        for (int j = 0; j < 8; j++)
            wf_t[c2 * 8 + j] = f2bf(Wf[row * 512 + col + j]);
    }
}

// ---------------- K3: top-16 (largest d2), one WAVE per point, no barriers ----------------
__global__ void __launch_bounds__(256, 4) knn_kernel(const float4* __restrict__ xn4,
                                                     unsigned short* __restrict__ idxout,
                                                     float* __restrict__ S9) {
    __shared__ float smom[4][15][9];
    int w = threadIdx.x >> 6, lane = threadIdx.x & 63;
    int i = blockIdx.x * 4 + w;
    int b = i >> 12, n = i & (N - 1);
    const float4* xb = xn4 + b * N;
    float4 qv = xb[n];
    float d[64];
    #pragma unroll
    for (int s = 0; s < 64; s++) {
        float4 p = xb[s * 64 + lane];
        d[s] = qv.w + p.w - 2.f * (qv.x * p.x + qv.y * p.y + qv.z * p.z);
    }
    float cm[8];
    #pragma unroll
    for (int c = 0; c < 8; c++) {
        float v = d[c * 8];
        #pragma unroll
        for (int s = 1; s < 8; s++) v = fmaxf(v, d[c * 8 + s]);
        cm[c] = v;
    }
    float bv = cm[0];
    #pragma unroll
    for (int c = 1; c < 8; c++) bv = fmaxf(bv, cm[c]);

    int myj = 0;
    for (int r = 0; r < 16; r++) {
        float wv = bv;
        #pragma unroll
        for (int off = 32; off > 0; off >>= 1)
            wv = fmaxf(wv, __shfl_xor(wv, off));
        unsigned long long msk = __ballot(bv == wv);
        int wl = __ffsll(msk) - 1;
        int gi = 0;
        if (lane == wl) {
            int cstar = 0; bool got = false;
            #pragma unroll
            for (int c = 0; c < 8; c++) {
                bool h = !got && (cm[c] == bv);
                cstar = h ? c : cstar;
                got = got || h;
            }
            int slot = 0;
            #pragma unroll
            for (int c = 0; c < 8; c++) {
                if (c == cstar) {   // 7 of 8 bodies skipped via execz
                    bool g2 = false;
                    #pragma unroll
                    for (int s = 0; s < 8; s++) {
                        bool h = !g2 && (d[c * 8 + s] == bv);
                        slot = h ? (c * 8 + s) : slot;
                        g2 = g2 || h;
                    }
                    #pragma unroll
                    for (int s = 0; s < 8; s++)
                        d[c * 8 + s] = (c * 8 + s == slot) ? -FLT_MAX : d[c * 8 + s];
                    float v = d[c * 8];
                    #pragma unroll
                    for (int s = 1; s < 8; s++) v = fmaxf(v, d[c * 8 + s]);
                    cm[c] = v;
                }
            }
            bv = cm[0];
            #pragma unroll
            for (int c = 1; c < 8; c++) bv = fmaxf(bv, cm[c]);
            gi = slot * 64 + lane;
        }
        int g = __shfl(gi, wl);
        if (lane == r - 1) myj = g;   // lanes 0..14 capture ranks 1..15
    }

    bool act = lane < 15;
    if (act) idxout[i * KNN + lane] = (unsigned short)myj;
    float4 pj = xb[act ? myj : n];
    float v0 = pj.x - qv.x, v1 = pj.y - qv.y, v2 = pj.z - qv.z;
    if (act) {
        float* mm = smom[w][lane];
        mm[0] = v0; mm[1] = v1; mm[2] = v2;
        mm[3] = v0 * v0; mm[4] = v1 * v1; mm[5] = v2 * v2;
        mm[6] = v0 * v1; mm[7] = v0 * v2; mm[8] = v1 * v2;
    }
    __syncthreads();
    int t = threadIdx.x;
    if (t < 36) {
        int wsel = t / 9, j = t % 9;
        float a = 0.f;
        #pragma unroll
        for (int u = 0; u < 15; u++) a += smom[wsel][u][j];
        atomicAdd(&S9[((blockIdx.x * 4 + wsel) & 63) * 9 + j], a);
    }
}

// ---------------- K5: closed-form BN2a affine + per-E fused (W2a*s, shift) float4 ----------------
__global__ void finalize_stats(const float* __restrict__ S9,
                               const float* __restrict__ g2a, const float* __restrict__ b2a,
                               const float* __restrict__ W2a,
                               const float* __restrict__ g2b, const float* __restrict__ b2b,
                               float* __restrict__ ab, float4* __restrict__ wsb) {
    const float cnt = (float)(BN_ * KNN);
    __shared__ float S[9];
    __shared__ float alpha[3], beta[3], mu[3], Ehh[3][3];
    int t = threadIdx.x;
    if (t < 9) {
        float a = 0.f;
        for (int u = 0; u < 64; u++) a += S9[u * 9 + t];
        S[t] = a;
    }
    __syncthreads();
    if (t == 0) {
        float m[3];
        float s2[3][3];
        s2[0][0] = S[3]; s2[1][1] = S[4]; s2[2][2] = S[5];
        s2[0][1] = s2[1][0] = S[6]; s2[0][2] = s2[2][0] = S[7]; s2[1][2] = s2[2][1] = S[8];
        for (int c = 0; c < 3; c++) {
            m[c] = S[c] / cnt;
            float var = s2[c][c] / cnt - m[c] * m[c];
            alpha[c] = g2a[c] * rsqrtf(var + EPS);
            beta[c]  = b2a[c] - m[c] * alpha[c];
            mu[c] = m[c];
            ab[c] = alpha[c]; ab[3 + c] = beta[c];
        }
        for (int c = 0; c < 3; c++)
            for (int cc = 0; cc < 3; cc++)
                Ehh[c][cc] = alpha[c] * alpha[cc] * (s2[c][cc] / cnt)
                           + alpha[c] * beta[cc] * m[c]
                           + beta[c] * alpha[cc] * m[cc]
                           + beta[c] * beta[cc];
    }
    __syncthreads();
    int e = t;
    float wv[3], Eh[3];
    for (int c = 0; c < 3; c++) { wv[c] = W2a[e * 3 + c]; Eh[c] = alpha[c] * mu[c] + beta[c]; }
    float mean = wv[0] * Eh[0] + wv[1] * Eh[1] + wv[2] * Eh[2];
    float m2 = 0.f;
    for (int c = 0; c < 3; c++)
        for (int cc = 0; cc < 3; cc++) m2 += wv[c] * wv[cc] * Ehh[c][cc];
    float var = m2 - mean * mean;
    float s = g2b[e] * rsqrtf(var + EPS);
    float4 o;
    o.x = wv[0] * s; o.y = wv[1] * s; o.z = wv[2] * s; o.w = b2b[e] - mean * s;
    wsb[e] = o;
}

// ---------------- K6: fused W2a→BN2b→gelu→[MFMA W2b]→max | point_emb | [MFMA Wf] ----------------
// Phase C uses R8's wave split (f-half x point-pair): hfr[2][8]=64 VGPRs keeps liveness
// under the 128-VGPR cap — R9's all-4-points split spilled to scratch (412 MB FETCH).
__global__ void __launch_bounds__(256, 4) fused_final(
        const float4* __restrict__ xn4, const unsigned short* __restrict__ idx,
        const float* __restrict__ ab,
        const float4* __restrict__ wsb,
        const unsigned short* __restrict__ w2b_t,
        const float* __restrict__ W1, const float* __restrict__ bw1,
        const unsigned short* __restrict__ wf_t, const float* __restrict__ bfv,
        float* __restrict__ out) {
    __shared__ __align__(16) unsigned short hh_bf[64 * SR];    // row n=16p+k, col e (bf16)
    __shared__ __align__(16) unsigned short feat_bf[4 * SRF];  // row p, col f 0..511 (bf16)
    __shared__ __align__(16) float4 hhat4[P][16];              // (h0,h1,h2,-) per (p,k)
    int i0 = blockIdx.x * P;
    int t = threadIdx.x;
    int b = i0 >> 12, n0 = i0 & (N - 1);
    const float4* xb = xn4 + b * N;

    if (t < P * KNN) {   // phase A: gather + BN2a affine
        int p = t / KNN, k = t % KNN;
        int j = idx[(i0 + p) * KNN + k];
        float4 pj = xb[j];
        float4 pn = xb[n0 + p];
        float4 h;
        h.x = ab[0] * (pj.x - pn.x) + ab[3];
        h.y = ab[1] * (pj.y - pn.y) + ab[4];
        h.z = ab[2] * (pj.z - pn.z) + ab[5];
        h.w = 0.f;
        hhat4[p][k] = h;
    }
    __syncthreads();

    {   // phase B: h = (W2a*s) @ hhat + shift, tanh-gelu (bf16 to LDS); point_emb
        int e = t;
        float4 w4 = wsb[e];   // (w0*s, w1*s, w2*s, shift)
        #pragma unroll
        for (int p = 0; p < P; p++) {
            float g0 = 0.f;
            #pragma unroll
            for (int k = 0; k < KNN; k++) {
                float4 hv = hhat4[p][k];
                float v = fmaf(w4.x, hv.x, fmaf(w4.y, hv.y, fmaf(w4.z, hv.z, w4.w)));
                float g = gelu_t(v);
                hh_bf[(16 * p + k) * SR + e] = f2bf(g);
                if (k == 0) g0 = g;
            }
            hh_bf[(16 * p + 15) * SR + e] = f2bf(g0);   // dup row: max unaffected
            float4 pv = xb[n0 + p];
            feat_bf[p * SRF + e] = f2bf(bw1[e] + W1[e * 3] * pv.x
                       + W1[e * 3 + 1] * pv.y + W1[e * 3 + 2] * pv.z);
        }
    }
    __syncthreads();

    int w = t >> 6, lane = t & 63;
    int m = lane & 15, q = lane >> 4;

    {   // phase C: D[k][f] = hh-tile x w2b-tile; max over k-rows -> feat_bf[:,256:512]
        int fh = w >> 1, pp = w & 1;
        bf8 hfr[2][8];
        #pragma unroll
        for (int pi = 0; pi < 2; pi++)
            #pragma unroll
            for (int kb = 0; kb < 8; kb++)
                hfr[pi][kb] = ld_bf8(&hh_bf[(16 * (pp * 2 + pi) + m) * SR + kb * 32 + q * 8]);

        const unsigned short* wbase = w2b_t + fh * 8 * 4096 + lane * 8;
        for (int ft = 0; ft < 8; ft++) {
            bf8 a[8];
            #pragma unroll
            for (int kb = 0; kb < 8; kb++)
                a[kb] = ld_bf8(wbase + ft * 4096 + kb * 512);
            #pragma unroll
            for (int pi = 0; pi < 2; pi++) {
                f4 acc = {0.f, 0.f, 0.f, 0.f};
                #pragma unroll
                for (int kb = 0; kb < 8; kb++)
                    acc = __builtin_amdgcn_mfma_f32_16x16x32_bf16(hfr[pi][kb], a[kb], acc, 0, 0, 0);
                float mx = fmaxf(fmaxf(acc[0], acc[1]), fmaxf(acc[2], acc[3]));
                mx = fmaxf(mx, __shfl_xor(mx, 16));
                mx = fmaxf(mx, __shfl_xor(mx, 32));
                if (lane < 16)
                    feat_bf[(pp * 2 + pi) * SRF + E + (fh * 8 + ft) * 16 + lane] = f2bf(mx);
            }
        }
    }
    __syncthreads();

    {   // phase D: out = Wf @ feat^T via MFMA (cols = points; feat fragments hoisted)
        bf8 fb[16];
        #pragma unroll
        for (int kb = 0; kb < 16; kb++)
            fb[kb] = ld_bf8(&feat_bf[(m & 3) * SRF + kb * 32 + q * 8]);
        const unsigned short* wfb = wf_t + w * 4 * 8192 + lane * 8;
        #pragma unroll
        for (int ot = 0; ot < 4; ot++) {
            f4 acc = {0.f, 0.f, 0.f, 0.f};
            #pragma unroll
            for (int kb = 0; kb < 16; kb++) {
                bf8 a = ld_bf8(wfb + ot * 8192 + kb * 512);
                acc = __builtin_amdgcn_mfma_f32_16x16x32_bf16(a, fb[kb], acc, 0, 0, 0);
            }
            if (m < P) {   // col = m = point; row = obase + 4q + reg
                int o0 = (w * 4 + ot) * 16 + 4 * q;
                out[(b * E + o0 + 0) * N + n0 + m] = acc[0] + bfv[o0 + 0];
                out[(b * E + o0 + 1) * N + n0 + m] = acc[1] + bfv[o0 + 1];
                out[(b * E + o0 + 2) * N + n0 + m] = acc[2] + bfv[o0 + 2];
                out[(b * E + o0 + 3) * N + n0 + m] = acc[3] + bfv[o0 + 3];
            }
        }
    }
}

extern "C" void kernel_launch(void* const* d_in, const int* in_sizes, int n_in,
                              void* d_out, int out_size, void* d_ws, size_t ws_size,
                              hipStream_t stream) {
    (void)in_sizes; (void)n_in; (void)out_size; (void)ws_size;
    const float* x   = (const float*)d_in[0];
    const float* g1  = (const float*)d_in[1];
    const float* b1  = (const float*)d_in[2];
    const float* W1  = (const float*)d_in[3];
    const float* bw1 = (const float*)d_in[4];
    const float* g2a = (const float*)d_in[5];
    const float* b2a = (const float*)d_in[6];
    const float* W2a = (const float*)d_in[7];
    const float* g2b = (const float*)d_in[8];
    const float* b2b = (const float*)d_in[9];
    const float* W2b = (const float*)d_in[10];
    const float* Wf  = (const float*)d_in[11];
    const float* bfv = (const float*)d_in[12];
    float* out = (float*)d_out;

    char* ws = (char*)d_ws;
    size_t off = 0;
    auto alloc = [&](size_t bytes) { size_t o = off; off = (off + bytes + 255) & ~(size_t)255; return o; };
    float4* xn4           = (float4*)(ws + alloc(sizeof(float4) * BN_));
    unsigned short* idx   = (unsigned short*)(ws + alloc(sizeof(unsigned short) * BN_ * KNN));
    float* bn1            = (float*)(ws + alloc(sizeof(float) * 8));
    float* S9             = (float*)(ws + alloc(sizeof(float) * 64 * 9));
    float* ab             = (float*)(ws + alloc(sizeof(float) * 8));
    float4* wsb           = (float4*)(ws + alloc(sizeof(float4) * E));
    unsigned short* w2bt  = (unsigned short*)(ws + alloc(sizeof(unsigned short) * E * E));
    unsigned short* wft   = (unsigned short*)(ws + alloc(sizeof(unsigned short) * E * 2 * E));

    hipMemsetAsync(S9, 0, sizeof(float) * 64 * 9, stream);

    bn1_stats<<<C, 256, 0, stream>>>(x, bn1);
    compute_xn_cvt<<<BN_ / 256 + (8192 + 16384) / 256, 256, 0, stream>>>(
        x, g1, b1, bn1, xn4, W2b, Wf, w2bt, wft);
    knn_kernel<<<BN_ / 4, 256, 0, stream>>>(xn4, idx, S9);
    finalize_stats<<<1, 256, 0, stream>>>(S9, g2a, b2a, W2a, g2b, b2b, ab, wsb);
    fused_final<<<BN_ / P, 256, 0, stream>>>(xn4, idx, ab, wsb, w2bt, W1, bw1, wft, bfv, out);
}

// Round 11
// 247.771 us; speedup vs baseline: 1.5689x; 1.0594x over previous
//
#include <hip/hip_runtime.h>
#include <float.h>
#include <math.h>

#define EPS 1e-5f
constexpr int B = 4, C = 3, N = 4096, E = 256;
constexpr int KNN = 15;            // 15 neighbors kept (top-16 minus rank 0)
constexpr int BN_ = B * N;         // 16384
constexpr int P = 8;               // points per block in fused kernel
constexpr int SR  = 264;           // hh_bf row stride (ushorts)
constexpr int SRF = 520;           // feat_bf row stride (ushorts)

typedef short bf8 __attribute__((ext_vector_type(8)));   // 8 bf16 in 4 VGPRs
typedef float f4  __attribute__((ext_vector_type(4)));

static __device__ __forceinline__ unsigned short f2bf(float f) {
    union { float f; unsigned int u; } v; v.f = f;
    unsigned int r = v.u + 0x7FFFu + ((v.u >> 16) & 1u);   // RTNE
    return (unsigned short)(r >> 16);
}
static __device__ __forceinline__ bf8 ld_bf8(const unsigned short* p) {
    return *(const bf8*)p;
}
// tanh-GELU: max |err| vs exact erf-gelu ~3e-4 (<< bf16 rounding).
static __device__ __forceinline__ float gelu_t(float v) {
    float z = v * fmaf(v * v, 0.07135482f, 1.59576912f);   // z = 2u
    float r = __builtin_amdgcn_rcpf(1.f + __expf(z));
    return fmaf(-v, r, v);
}

// ---------------- K1: per-channel mean/rstd of x over (B,N) ----------------
__global__ void bn1_stats(const float* __restrict__ x, float* __restrict__ bn1) {
    int c = blockIdx.x, t = threadIdx.x;
    float s = 0.f, ss = 0.f;
    for (int i4 = t; i4 < BN_ / 4; i4 += 256) {
        int b = i4 >> 10, n4 = i4 & 1023;
        float4 v = ((const float4*)(x + (b * C + c) * N))[n4];
        s += v.x + v.y + v.z + v.w;
        ss += v.x * v.x + v.y * v.y + v.z * v.z + v.w * v.w;
    }
    __shared__ float rs_[256], rss_[256];
    rs_[t] = s; rss_[t] = ss; __syncthreads();
    for (int w = 128; w > 0; w >>= 1) {
        if (t < w) { rs_[t] += rs_[t + w]; rss_[t] += rss_[t + w]; }
        __syncthreads();
    }
    if (t == 0) {
        float mu = rs_[0] / (float)BN_;
        float var = rss_[0] / (float)BN_ - mu * mu;
        bn1[c] = mu; bn1[3 + c] = rsqrtf(var + EPS);
    }
}

// ---------------- K2: xn4 AoS (blocks 0..63) + tile-lane-major bf16 weights ----------------
// w2b_t: chunk (ft*8+kb)*64+lane holds W2b[ft*16+(lane&15)][kb*32+(lane>>4)*8 ..+8]  (ft-stride 4096)
// wf_t : chunk (ot*16+kb)*64+lane holds Wf[ot*16+(lane&15)][kb*32+(lane>>4)*8 ..+8]  (ot-stride 8192)
__global__ void compute_xn_cvt(const float* __restrict__ x,
                               const float* __restrict__ g1,
                               const float* __restrict__ b1,
                               const float* __restrict__ bn1,
                               float4* __restrict__ xn4,
                               const float* __restrict__ W2b, const float* __restrict__ Wf,
                               unsigned short* __restrict__ w2b_t, unsigned short* __restrict__ wf_t) {
    int blk = blockIdx.x;
    if (blk < BN_ / 256) {
        int i = blk * 256 + threadIdx.x;
        int b = i >> 12, n = i & (N - 1);
        float v[3];
        #pragma unroll
        for (int c = 0; c < C; c++)
            v[c] = (x[(b * C + c) * N + n] - bn1[c]) * bn1[3 + c] * g1[c] + b1[c];
        float4 o; o.x = v[0]; o.y = v[1]; o.z = v[2];
        o.w = v[0] * v[0] + v[1] * v[1] + v[2] * v[2];
        xn4[i] = o;
        return;
    }
    int ch = (blk - BN_ / 256) * 256 + threadIdx.x;   // chunk id (8 bf16 per chunk)
    if (ch < 8192) {               // w2b: 65536 elems = 8192 chunks
        int lane = ch & 63, kb = (ch >> 6) & 7, ft16 = ch >> 9;
        int row = ft16 * 16 + (lane & 15);
        int col = kb * 32 + (lane >> 4) * 8;
        #pragma unroll
        for (int j = 0; j < 8; j++)
            w2b_t[ch * 8 + j] = f2bf(W2b[row * 256 + col + j]);
    } else {                       // wf: 131072 elems = 16384 chunks
        int c2 = ch - 8192;
        int lane = c2 & 63, kb = (c2 >> 6) & 15, ot = c2 >> 10;
        int row = ot * 16 + (lane & 15);
        int col = kb * 32 + (lane >> 4) * 8;
        #pragma unroll
        for (int j = 0; j < 8; j++)
            wf_t[c2 * 8 + j] = f2bf(Wf[row * 512 + col + j]);
    }
}

// ---------------- K3: top-16 (largest d2), one WAVE per point, no barriers ----------------
__global__ void __launch_bounds__(256, 4) knn_kernel(const float4* __restrict__ xn4,
                                                     unsigned short* __restrict__ idxout,
                                                     float* __restrict__ S9) {
    __shared__ float smom[4][15][9];
    int w = threadIdx.x >> 6, lane = threadIdx.x & 63;
    int i = blockIdx.x * 4 + w;
    int b = i >> 12, n = i & (N - 1);
    const float4* xb = xn4 + b * N;
    float4 qv = xb[n];
    float d[64];
    #pragma unroll
    for (int s = 0; s < 64; s++) {
        float4 p = xb[s * 64 + lane];
        d[s] = qv.w + p.w - 2.f * (qv.x * p.x + qv.y * p.y + qv.z * p.z);
    }
    float cm[8];
    #pragma unroll
    for (int c = 0; c < 8; c++) {
        float v = d[c * 8];
        #pragma unroll
        for (int s = 1; s < 8; s++) v = fmaxf(v, d[c * 8 + s]);
        cm[c] = v;
    }
    float bv = cm[0];
    #pragma unroll
    for (int c = 1; c < 8; c++) bv = fmaxf(bv, cm[c]);

    int myj = 0;
    for (int r = 0; r < 16; r++) {
        float wv = bv;
        #pragma unroll
        for (int off = 32; off > 0; off >>= 1)
            wv = fmaxf(wv, __shfl_xor(wv, off));
        unsigned long long msk = __ballot(bv == wv);
        int wl = __ffsll(msk) - 1;
        int gi = 0;
        if (lane == wl) {
            int cstar = 0; bool got = false;
            #pragma unroll
            for (int c = 0; c < 8; c++) {
                bool h = !got && (cm[c] == bv);
                cstar = h ? c : cstar;
                got = got || h;
            }
            int slot = 0;
            #pragma unroll
            for (int c = 0; c < 8; c++) {
                if (c == cstar) {   // 7 of 8 bodies skipped via execz
                    bool g2 = false;
                    #pragma unroll
                    for (int s = 0; s < 8; s++) {
                        bool h = !g2 && (d[c * 8 + s] == bv);
                        slot = h ? (c * 8 + s) : slot;
                        g2 = g2 || h;
                    }
                    #pragma unroll
                    for (int s = 0; s < 8; s++)
                        d[c * 8 + s] = (c * 8 + s == slot) ? -FLT_MAX : d[c * 8 + s];
                    float v = d[c * 8];
                    #pragma unroll
                    for (int s = 1; s < 8; s++) v = fmaxf(v, d[c * 8 + s]);
                    cm[c] = v;
                }
            }
            bv = cm[0];
            #pragma unroll
            for (int c = 1; c < 8; c++) bv = fmaxf(bv, cm[c]);
            gi = slot * 64 + lane;
        }
        int g = __shfl(gi, wl);
        if (lane == r - 1) myj = g;   // lanes 0..14 capture ranks 1..15
    }

    bool act = lane < 15;
    if (act) idxout[i * KNN + lane] = (unsigned short)myj;
    float4 pj = xb[act ? myj : n];
    float v0 = pj.x - qv.x, v1 = pj.y - qv.y, v2 = pj.z - qv.z;
    if (act) {
        float* mm = smom[w][lane];
        mm[0] = v0; mm[1] = v1; mm[2] = v2;
        mm[3] = v0 * v0; mm[4] = v1 * v1; mm[5] = v2 * v2;
        mm[6] = v0 * v1; mm[7] = v0 * v2; mm[8] = v1 * v2;
    }
    __syncthreads();
    int t = threadIdx.x;
    if (t < 36) {
        int wsel = t / 9, j = t % 9;
        float a = 0.f;
        #pragma unroll
        for (int u = 0; u < 15; u++) a += smom[wsel][u][j];
        atomicAdd(&S9[((blockIdx.x * 4 + wsel) & 63) * 9 + j], a);
    }
}

// ---------------- K5: closed-form BN2a affine + per-E fused (W2a*s, shift) float4 ----------------
__global__ void finalize_stats(const float* __restrict__ S9,
                               const float* __restrict__ g2a, const float* __restrict__ b2a,
                               const float* __restrict__ W2a,
                               const float* __restrict__ g2b, const float* __restrict__ b2b,
                               float* __restrict__ ab, float4* __restrict__ wsb) {
    const float cnt = (float)(BN_ * KNN);
    __shared__ float S[9];
    __shared__ float alpha[3], beta[3], mu[3], Ehh[3][3];
    int t = threadIdx.x;
    if (t < 9) {
        float a = 0.f;
        for (int u = 0; u < 64; u++) a += S9[u * 9 + t];
        S[t] = a;
    }
    __syncthreads();
    if (t == 0) {
        float m[3];
        float s2[3][3];
        s2[0][0] = S[3]; s2[1][1] = S[4]; s2[2][2] = S[5];
        s2[0][1] = s2[1][0] = S[6]; s2[0][2] = s2[2][0] = S[7]; s2[1][2] = s2[2][1] = S[8];
        for (int c = 0; c < 3; c++) {
            m[c] = S[c] / cnt;
            float var = s2[c][c] / cnt - m[c] * m[c];
            alpha[c] = g2a[c] * rsqrtf(var + EPS);
            beta[c]  = b2a[c] - m[c] * alpha[c];
            mu[c] = m[c];
            ab[c] = alpha[c]; ab[3 + c] = beta[c];
        }
        for (int c = 0; c < 3; c++)
            for (int cc = 0; cc < 3; cc++)
                Ehh[c][cc] = alpha[c] * alpha[cc] * (s2[c][cc] / cnt)
                           + alpha[c] * beta[cc] * m[c]
                           + beta[c] * alpha[cc] * m[cc]
                           + beta[c] * beta[cc];
    }
    __syncthreads();
    int e = t;
    float wv[3], Eh[3];
    for (int c = 0; c < 3; c++) { wv[c] = W2a[e * 3 + c]; Eh[c] = alpha[c] * mu[c] + beta[c]; }
    float mean = wv[0] * Eh[0] + wv[1] * Eh[1] + wv[2] * Eh[2];
    float m2 = 0.f;
    for (int c = 0; c < 3; c++)
        for (int cc = 0; cc < 3; cc++) m2 += wv[c] * wv[cc] * Ehh[c][cc];
    float var = m2 - mean * mean;
    float s = g2b[e] * rsqrtf(var + EPS);
    float4 o;
    o.x = wv[0] * s; o.y = wv[1] * s; o.z = wv[2] * s; o.w = b2b[e] - mean * s;
    wsb[e] = o;
}

// ---------------- K6: fused, P=8, 512 threads: full weight dedup ----------------
// Phase C: wave w owns f-tiles {2w, 2w+1}; each w2b tile loaded ONCE per block;
// point-pairs looped with unroll-1 (max 2 concurrent MFMA chains -> no spill; R9 lesson).
// Phase D: wave w owns o-tiles {2w, 2w+1}; 8 valid point-cols (50% MFMA efficiency).
__global__ void __launch_bounds__(512, 4) fused_final(
        const float4* __restrict__ xn4, const unsigned short* __restrict__ idx,
        const float* __restrict__ ab,
        const float4* __restrict__ wsb,
        const unsigned short* __restrict__ w2b_t,
        const float* __restrict__ W1, const float* __restrict__ bw1,
        const unsigned short* __restrict__ wf_t, const float* __restrict__ bfv,
        float* __restrict__ out) {
    __shared__ __align__(16) unsigned short hh_bf[128 * SR];   // row n=16p+k (p<8), col e
    __shared__ __align__(16) unsigned short feat_bf[8 * SRF];  // row p, col f 0..511
    __shared__ __align__(16) float4 hhat4[P][16];              // (h0,h1,h2,-) per (p,k)
    int i0 = blockIdx.x * P;
    int t = threadIdx.x;
    int b = i0 >> 12, n0 = i0 & (N - 1);
    const float4* xb = xn4 + b * N;

    if (t < P * KNN) {   // phase A: gather + BN2a affine (120 threads)
        int p = t / KNN, k = t % KNN;
        int j = idx[(i0 + p) * KNN + k];
        float4 pj = xb[j];
        float4 pn = xb[n0 + p];
        float4 h;
        h.x = ab[0] * (pj.x - pn.x) + ab[3];
        h.y = ab[1] * (pj.y - pn.y) + ab[4];
        h.z = ab[2] * (pj.z - pn.z) + ab[5];
        h.w = 0.f;
        hhat4[p][k] = h;
    }
    __syncthreads();

    {   // phase B: h = (W2a*s) @ hhat + shift, tanh-gelu (bf16 to LDS); point_emb
        int e = t & 255;
        int ph = t >> 8;             // half: points 4*ph .. 4*ph+3
        float4 w4 = wsb[e];          // (w0*s, w1*s, w2*s, shift)
        #pragma unroll
        for (int pp = 0; pp < 4; pp++) {
            int p = ph * 4 + pp;
            float g0 = 0.f;
            #pragma unroll
            for (int k = 0; k < KNN; k++) {
                float4 hv = hhat4[p][k];
                float v = fmaf(w4.x, hv.x, fmaf(w4.y, hv.y, fmaf(w4.z, hv.z, w4.w)));
                float g = gelu_t(v);
                hh_bf[(16 * p + k) * SR + e] = f2bf(g);
                if (k == 0) g0 = g;
            }
            hh_bf[(16 * p + 15) * SR + e] = f2bf(g0);   // dup row: max unaffected
            float4 pv = xb[n0 + p];
            feat_bf[p * SRF + e] = f2bf(bw1[e] + W1[e * 3] * pv.x
                       + W1[e * 3 + 1] * pv.y + W1[e * 3 + 2] * pv.z);
        }
    }
    __syncthreads();

    int w = t >> 6, lane = t & 63;
    int m = lane & 15, q = lane >> 4;

    {   // phase C: wave w -> f-tiles {2w, 2w+1}, all 8 points via 4 point-pairs
        #pragma unroll
        for (int f = 0; f < 2; f++) {
            int ft = w * 2 + f;
            bf8 a[8];
            #pragma unroll
            for (int kb = 0; kb < 8; kb++)
                a[kb] = ld_bf8(w2b_t + ft * 4096 + kb * 512 + lane * 8);
            #pragma unroll 1
            for (int pr = 0; pr < 4; pr++) {
                bf8 hfr[2][8];
                #pragma unroll
                for (int pi = 0; pi < 2; pi++)
                    #pragma unroll
                    for (int kb = 0; kb < 8; kb++)
                        hfr[pi][kb] = ld_bf8(&hh_bf[(16 * (pr * 2 + pi) + m) * SR + kb * 32 + q * 8]);
                #pragma unroll
                for (int pi = 0; pi < 2; pi++) {
                    f4 acc = {0.f, 0.f, 0.f, 0.f};
                    #pragma unroll
                    for (int kb = 0; kb < 8; kb++)
                        acc = __builtin_amdgcn_mfma_f32_16x16x32_bf16(hfr[pi][kb], a[kb], acc, 0, 0, 0);
                    float mx = fmaxf(fmaxf(acc[0], acc[1]), fmaxf(acc[2], acc[3]));
                    mx = fmaxf(mx, __shfl_xor(mx, 16));
                    mx = fmaxf(mx, __shfl_xor(mx, 32));
                    if (lane < 16)
                        feat_bf[(pr * 2 + pi) * SRF + E + ft * 16 + lane] = f2bf(mx);
                }
            }
        }
    }
    __syncthreads();

    {   // phase D: wave w -> o-tiles {2w, 2w+1}; cols = 8 points (m&7)
        bf8 fb[16];
        #pragma unroll
        for (int kb = 0; kb < 16; kb++)
            fb[kb] = ld_bf8(&feat_bf[(m & 7) * SRF + kb * 32 + q * 8]);
        #pragma unroll
        for (int o2 = 0; o2 < 2; o2++) {
            int ot = w * 2 + o2;
            f4 acc = {0.f, 0.f, 0.f, 0.f};
            #pragma unroll
            for (int kb = 0; kb < 16; kb++) {
                bf8 a = ld_bf8(wf_t + ot * 8192 + kb * 512 + lane * 8);
                acc = __builtin_amdgcn_mfma_f32_16x16x32_bf16(a, fb[kb], acc, 0, 0, 0);
            }
            if (m < P) {   // col = m = point; row = ot*16 + 4q + reg
                int o0 = ot * 16 + 4 * q;
                out[(b * E + o0 + 0) * N + n0 + m] = acc[0] + bfv[o0 + 0];
                out[(b * E + o0 + 1) * N + n0 + m] = acc[1] + bfv[o0 + 1];
                out[(b * E + o0 + 2) * N + n0 + m] = acc[2] + bfv[o0 + 2];
                out[(b * E + o0 + 3) * N + n0 + m] = acc[3] + bfv[o0 + 3];
            }
        }
    }
}

extern "C" void kernel_launch(void* const* d_in, const int* in_sizes, int n_in,
                              void* d_out, int out_size, void* d_ws, size_t ws_size,
                              hipStream_t stream) {
    (void)in_sizes; (void)n_in; (void)out_size; (void)ws_size;
    const float* x   = (const float*)d_in[0];
    const float* g1  = (const float*)d_in[1];
    const float* b1  = (const float*)d_in[2];
    const float* W1  = (const float*)d_in[3];
    const float* bw1 = (const float*)d_in[4];
    const float* g2a = (const float*)d_in[5];
    const float* b2a = (const float*)d_in[6];
    const float* W2a = (const float*)d_in[7];
    const float* g2b = (const float*)d_in[8];
    const float* b2b = (const float*)d_in[9];
    const float* W2b = (const float*)d_in[10];
    const float* Wf  = (const float*)d_in[11];
    const float* bfv = (const float*)d_in[12];
    float* out = (float*)d_out;

    char* ws = (char*)d_ws;
    size_t off = 0;
    auto alloc = [&](size_t bytes) { size_t o = off; off = (off + bytes + 255) & ~(size_t)255; return o; };
    float4* xn4           = (float4*)(ws + alloc(sizeof(float4) * BN_));
    unsigned short* idx   = (unsigned short*)(ws + alloc(sizeof(unsigned short) * BN_ * KNN));
    float* bn1            = (float*)(ws + alloc(sizeof(float) * 8));
    float* S9             = (float*)(ws + alloc(sizeof(float) * 64 * 9));
    float* ab             = (float*)(ws + alloc(sizeof(float) * 8));
    float4* wsb           = (float4*)(ws + alloc(sizeof(float4) * E));
    unsigned short* w2bt  = (unsigned short*)(ws + alloc(sizeof(unsigned short) * E * E));
    unsigned short* wft   = (unsigned short*)(ws + alloc(sizeof(unsigned short) * E * 2 * E));

    hipMemsetAsync(S9, 0, sizeof(float) * 64 * 9, stream);

    bn1_stats<<<C, 256, 0, stream>>>(x, bn1);
    compute_xn_cvt<<<BN_ / 256 + (8192 + 16384) / 256, 256, 0, stream>>>(
        x, g1, b1, bn1, xn4, W2b, Wf, w2bt, wft);
    knn_kernel<<<BN_ / 4, 256, 0, stream>>>(xn4, idx, S9);
    finalize_stats<<<1, 256, 0, stream>>>(S9, g2a, b2a, W2a, g2b, b2b, ab, wsb);
    fused_final<<<BN_ / P, 512, 0, stream>>>(xn4, idx, ab, wsb, w2bt, W1, bw1, wft, bfv, out);
}